// Round 12
// baseline (155.651 us; speedup 1.0000x reference)
//
#include <hip/hip_runtime.h>

typedef __bf16 bf16;
typedef __bf16 bf16x8 __attribute__((ext_vector_type(8)));
typedef float f32x2 __attribute__((ext_vector_type(2)));
typedef float f32x4 __attribute__((ext_vector_type(4)));
typedef float f32x16 __attribute__((ext_vector_type(16)));
typedef unsigned int u32;
typedef u32 u32x2 __attribute__((ext_vector_type(2)));
typedef u32 u32x4 __attribute__((ext_vector_type(4)));

#define MFMA16(A,B,C) __builtin_amdgcn_mfma_f32_16x16x32_bf16(A,B,C,0,0,0)
#define MFMA32(A,B,C) __builtin_amdgcn_mfma_f32_32x32x16_bf16(A,B,C,0,0,0)

#define ALPHA 0.18033688f          /* 0.125 * log2(e): folded into Q          */
#define LOG2E 1.44269504f

static __device__ __forceinline__ u32 cvt_pk_bf16(float lo, float hi) {
    u32 r;
    asm("v_cvt_pk_bf16_f32 %0, %1, %2" : "=v"(r) : "v"(lo), "v"(hi));
    return r;
}
static __device__ __forceinline__ void permlane32_swap(u32& a, u32& b) {
    asm("v_permlane32_swap_b32 %0, %1" : "+v"(a), "+v"(b));
}
// single-instruction 2^x / 1/x (vs libm's multi-inst wrappers); ~1ulp approx.
static __device__ __forceinline__ float vexp2(float x) {
    float r;
    asm("v_exp_f32 %0, %1" : "=v"(r) : "v"(x));
    return r;
}
static __device__ __forceinline__ float vrcp(float x) {
    float r;
    asm("v_rcp_f32 %0, %1" : "=v"(r) : "v"(x));
    return r;
}
// async global->LDS DMA, 16B/lane; LDS dest = uniform base + lane*16 (HW).
static __device__ __forceinline__ void stage16(const bf16* g, bf16* l) {
    __builtin_amdgcn_global_load_lds(
        (const __attribute__((address_space(1))) void*)g,
        (__attribute__((address_space(3))) void*)l, 16, 0, 0);
}

// ---------------------------------------------------------------------------
// Kernel 0 (wprep): fold BN1/BN2 into kq weights+biases, bnl into out_w,
// Q-scale into Q rows; weights -> bf16. [r5-proven verbatim]
// ---------------------------------------------------------------------------
__global__ __launch_bounds__(64) void wprep_kernel(
    const float* __restrict__ kq1w, const float* __restrict__ kq1b,
    const float* __restrict__ bn1w, const float* __restrict__ bn1b,
    const float* __restrict__ bn1m, const float* __restrict__ bn1v,
    const float* __restrict__ kq2w, const float* __restrict__ kq2b,
    const float* __restrict__ bn2w, const float* __restrict__ bn2b,
    const float* __restrict__ bn2m, const float* __restrict__ bn2v,
    const float* __restrict__ vw,   const float* __restrict__ vb,
    const float* __restrict__ outw, const float* __restrict__ outb,
    const float* __restrict__ bnlw, const float* __restrict__ bnlb,
    const float* __restrict__ bnlm, const float* __restrict__ bnlv,
    bf16* __restrict__ Wk1, bf16* __restrict__ Wk2, bf16* __restrict__ Wv,
    bf16* __restrict__ Wo,
    float* __restrict__ B1, float* __restrict__ B2, float* __restrict__ Bv,
    float* __restrict__ Bo)
{
    const int blk = blockIdx.x, lane = threadIdx.x;
    if (blk < 384) {
        const int arr = blk >> 7, j = blk & 127;
        const float* W  = arr == 0 ? kq1w : arr == 1 ? kq2w : vw;
        const float* bs = arr == 0 ? kq1b : arr == 1 ? kq2b : vb;
        bf16*  Wd = arr == 0 ? Wk1 : arr == 1 ? Wk2 : Wv;
        float* Bd = arr == 0 ? B1  : arr == 1 ? B2  : Bv;
        const float scale = (arr < 2 && ((j >> 5) & 1)) ? ALPHA : 1.0f;
        const int c0 = lane * 4;
        f32x4 w4 = *(const f32x4*)(W + j * 256 + c0);
        f32x4 o4; float dot = 0.f;
        if (arr < 2) {
            const float* bw = arr ? bn2w : bn1w;
            const float* bb = arr ? bn2b : bn1b;
            const float* bm = arr ? bn2m : bn1m;
            const float* bv = arr ? bn2v : bn1v;
            f32x4 gw = *(const f32x4*)(bw + c0), gb = *(const f32x4*)(bb + c0);
            f32x4 gm = *(const f32x4*)(bm + c0), gv = *(const f32x4*)(bv + c0);
#pragma unroll
            for (int k = 0; k < 4; ++k) {
                float iv = gw[k] * rsqrtf(gv[k] + 1e-5f);
                float beta = gb[k] - gm[k] * iv;
                o4[k] = w4[k] * iv * scale;
                dot += w4[k] * beta;
            }
        } else {
#pragma unroll
            for (int k = 0; k < 4; ++k) o4[k] = w4[k];
        }
        u32x2 pk; pk[0] = cvt_pk_bf16(o4[0], o4[1]); pk[1] = cvt_pk_bf16(o4[2], o4[3]);
        *(u32x2*)(Wd + j * 256 + c0) = pk;
#pragma unroll
        for (int off = 32; off >= 1; off >>= 1) dot += __shfl_xor(dot, off);
        if (lane == 0) Bd[j] = (bs[j] + dot) * scale;
    } else {
        const int c = blk - 384;
        const float iv = bnlw[c] * rsqrtf(bnlv[c] + 1e-5f);
        const int k0 = lane * 2;
        f32x2 w2 = *(const f32x2*)(outw + c * 128 + k0);
        *(u32*)(Wo + c * 128 + k0) = cvt_pk_bf16(w2[0] * iv, w2[1] * iv);
        if (lane == 0) Bo[c] = outb[c] * iv + bnlb[c] - bnlm[c] * iv;
    }
}

// ---------------------------------------------------------------------------
// Kernel 1 (prep): D[j][n] = W' . X^T  (BN pre-folded). One mode per block.
// Fragment-major K/V layouts for attn's LDS staging [r7-proven]:
//   Kp[bh][kbg][chunk(512)][8]: chunk = ((kt*4+ds)*2+hi)*32 + l31
//   Vp[bh][kbg][chunk][8]:      chunk = ((dt*4+ks)*2+hi)*32 + (d&31), inner=key&7
// [r9-proven verbatim]
// ---------------------------------------------------------------------------
template<int MODE>
static __device__ __forceinline__ void prep_mode(
    const float* __restrict__ X, const bf16* __restrict__ W,
    const float* __restrict__ B,
    int b, int n, int g, int l15, int cibase,
    bf16* __restrict__ Kp, bf16* __restrict__ Q, bf16* __restrict__ Vp)
{
    const f32x4 z4 = {0.f, 0.f, 0.f, 0.f};
    f32x4 acc[4] = {z4, z4, z4, z4};
    const float* Xb = X + b * 256 * 4096;
#pragma unroll
    for (int ks = 0; ks < 8; ++ks) {
        const int c0 = ks * 32 + g * 8;
        bf16x8 bfr;
#pragma unroll
        for (int jj = 0; jj < 8; ++jj) bfr[jj] = (bf16)Xb[(c0 + jj) * 4096 + n];
#pragma unroll
        for (int ci = 0; ci < 4; ++ci) {
            bf16x8 af = *(const bf16x8*)(W + ((cibase + ci) * 16 + l15) * 256 + c0);
            acc[ci] = MFMA16(af, bfr, acc[ci]);
        }
    }
#pragma unroll
    for (int ci = 0; ci < 4; ++ci) {
        const int cia = cibase + ci;
        const int j0 = cia * 16 + g * 4;
        const f32x4 bq = *(const f32x4*)(B + j0);
        float v0 = acc[ci][0] + bq[0], v1 = acc[ci][1] + bq[1];
        float v2 = acc[ci][2] + bq[2], v3 = acc[ci][3] + bq[3];
        if constexpr (MODE == 2) {
            const int head = cia >> 2;
            const int bh = b * 2 + head;
            const int dbase = (cia & 3) * 16 + g * 4;
            const int kbg = n >> 6, key = n & 63;
            const int kc = key >> 4, hi2 = (key >> 3) & 1, inner = key & 7;
            bf16* vp = Vp + (size_t)(bh * 64 + kbg) * 4096;
            const float vv[4] = {v0, v1, v2, v3};
#pragma unroll
            for (int rr = 0; rr < 4; ++rr) {
                const int d = dbase + rr;
                const int chunk = (((d >> 5) * 4 + kc) * 2 + hi2) * 32 + (d & 31);
                vp[chunk * 8 + inner] = (bf16)vv[rr];
            }
        } else {
            const int seg = cia >> 1;          // 0:K h0  1:Q h0  2:K h1  3:Q h1
            const int head = seg >> 1;
            const int bh = b * 2 + head;
            const int d0 = (cia & 1) * 16 + g * 4 + (MODE == 1 ? 32 : 0);
            u32x2 pk; pk[0] = cvt_pk_bf16(v0, v1); pk[1] = cvt_pk_bf16(v2, v3);
            if (seg & 1) {
                *(u32x2*)(Q + ((size_t)bh * 4096 + n) * 64 + d0) = pk;
            } else {
                const int kbg = n >> 6, r = n & 63;
                const int chunk = (((r >> 5) * 4 + (d0 >> 4)) * 2 + ((d0 >> 3) & 1)) * 32 + (r & 31);
                *(u32x2*)(Kp + (size_t)(bh * 64 + kbg) * 4096 + chunk * 8 + (d0 & 7)) = pk;
            }
        }
    }
}

__global__ __launch_bounds__(256) void prep_kernel(
    const float* __restrict__ rgb, const float* __restrict__ dsm,
    const float* __restrict__ fus,
    const bf16* __restrict__ Wk1, const bf16* __restrict__ Wk2,
    const bf16* __restrict__ Wv,
    const float* __restrict__ B1, const float* __restrict__ B2,
    const float* __restrict__ Bv,
    bf16* __restrict__ Kp, bf16* __restrict__ Q, bf16* __restrict__ Vp)
{
    const int id = blockIdx.x;
    const int mode = id >> 9, sub = id & 511;
    const int b = sub >> 7, nt = sub & 127;
    const int t = threadIdx.x, lane = t & 63, w = t >> 6;
    const int l15 = lane & 15, g = lane >> 4;
    const int n = nt * 32 + (w & 1) * 16 + l15;
    const int cibase = (w >> 1) * 4;

    if (mode == 0)      prep_mode<0>(rgb, Wk1, B1, b, n, g, l15, cibase, Kp, Q, Vp);
    else if (mode == 1) prep_mode<1>(dsm, Wk2, B2, b, n, g, l15, cibase, Kp, Q, Vp);
    else                prep_mode<2>(fus, Wv,  Bv, b, n, g, l15, cibase, Kp, Q, Vp);
}

// ---------------------------------------------------------------------------
// Kernel 2 (attn): split-K x8, LDS-staged K/V, 512-thr/8-wave blocks, m=0
// softmax [r11 body]. NEW sync structure (T4): counted vmcnt + raw barriers,
// 2-tile-deep DMA pipeline -- the next tiles' global_load_lds stay in flight
// ACROSS barriers (never vmcnt(0) except the final iteration), removing the
// per-kb drain that __syncthreads imposed.
// Invariants: tile t -> buffer t&1; vmcnt retires in order; per kb:
//   vmcnt(2)=tile kb landed -> barrier (cross-wave visibility) -> compute ->
//   barrier (read-complete) -> STAGE(kb&1, kb+2).
// ---------------------------------------------------------------------------
__global__ __launch_bounds__(512) void attn_kernel(
    const bf16* __restrict__ Kp, const bf16* __restrict__ Q,
    const bf16* __restrict__ Vp,
    bf16* __restrict__ Opart, float* __restrict__ Ml)
{
    __shared__ __align__(16) bf16 sK[2][4096];
    __shared__ __align__(16) bf16 sV[2][4096];

    const int id = blockIdx.x;                    // 1024
    const int bh = id & 7;                        // XCD-local
    const int qt = (id >> 3) & 15;
    const int s  = id >> 7;                       // 0..7

    const int t = threadIdx.x, lane = t & 63, w = t >> 6;   // w in 0..7
    const int l31 = lane & 31, hi = lane >> 5;
    const int qrow = qt * 256 + w * 32 + l31;
    const int base = bh * 4096;

    bf16x8 qf[4];
    {
        const bf16* qp = Q + ((size_t)(base + qrow)) * 64 + hi * 8;
#pragma unroll
        for (int ds = 0; ds < 4; ++ds) qf[ds] = *(const bf16x8*)(qp + ds * 16);
    }

    f32x16 ot0, ot1;
#pragma unroll
    for (int i = 0; i < 16; ++i) { ot0[i] = 0.f; ot1[i] = 0.f; }
    float lsum = 0.f;

    const bf16* Kblk = Kp + (size_t)(bh * 64 + s * 8) * 4096;
    const bf16* Vblk = Vp + (size_t)(bh * 64 + s * 8) * 4096;
    const int wo = w * 512 + lane * 8;            // covers 4096 elems over 8 waves

#define STAGE(BUF, KBI)                                                      \
    {                                                                        \
        const size_t gb = (size_t)(KBI) * 4096 + wo;                         \
        stage16(Kblk + gb, &sK[BUF][w * 512]);                               \
        stage16(Vblk + gb, &sV[BUF][w * 512]);                               \
    }

    // prologue: tiles 0 and 1 in flight (4 loads/wave)
    STAGE(0, 0);
    STAGE(1, 1);

#pragma unroll
    for (int kb = 0; kb < 8; ++kb) {
        // wait tile kb (issued 2 iters back); tile kb+1's loads stay in flight
        if (kb == 7) { asm volatile("s_waitcnt vmcnt(0)" ::: "memory"); }
        else         { asm volatile("s_waitcnt vmcnt(2)" ::: "memory"); }
        __builtin_amdgcn_s_barrier();             // all waves' chunks landed

        const bf16* Kl = &sK[kb & 1][0];
        const bf16* Vl = &sV[kb & 1][0];

        // ---- per kt: QK^T -> exp2 on accumulator -> sum -> bf16 frags ----
        bf16x8 pa[4];
#pragma unroll
        for (int kt = 0; kt < 2; ++kt) {
            f32x16 a;
#pragma unroll
            for (int i = 0; i < 16; ++i) a[i] = 0.f;
#pragma unroll
            for (int ds = 0; ds < 4; ++ds)
                a = MFMA32(*(const bf16x8*)(Kl + (kt * 4 + ds) * 512 + lane * 8), qf[ds], a);
#pragma unroll
            for (int r = 0; r < 16; ++r) a[r] = vexp2(a[r]);
            lsum += (((a[0] + a[1]) + (a[2] + a[3])) +
                     ((a[4] + a[5]) + (a[6] + a[7]))) +
                    (((a[8] + a[9]) + (a[10] + a[11])) +
                     ((a[12] + a[13]) + (a[14] + a[15])));
            u32 wa0 = cvt_pk_bf16(a[0], a[1]);
            u32 wa1 = cvt_pk_bf16(a[2], a[3]);
            u32 wb0 = cvt_pk_bf16(a[4], a[5]);
            u32 wb1 = cvt_pk_bf16(a[6], a[7]);
            permlane32_swap(wa0, wb0);
            permlane32_swap(wa1, wb1);
            u32x4 pk0; pk0[0] = wa0; pk0[1] = wa1; pk0[2] = wb0; pk0[3] = wb1;
            pa[2 * kt] = __builtin_bit_cast(bf16x8, pk0);
            u32 wc0 = cvt_pk_bf16(a[8], a[9]);
            u32 wc1 = cvt_pk_bf16(a[10], a[11]);
            u32 wd0 = cvt_pk_bf16(a[12], a[13]);
            u32 wd1 = cvt_pk_bf16(a[14], a[15]);
            permlane32_swap(wc0, wd0);
            permlane32_swap(wc1, wd1);
            u32x4 pk1; pk1[0] = wc0; pk1[1] = wc1; pk1[2] = wd0; pk1[3] = wd1;
            pa[2 * kt + 1] = __builtin_bit_cast(bf16x8, pk1);
        }
        // ---- O^T += V^T . P  (frag i=dt*4+ks) ----
#pragma unroll
        for (int ks = 0; ks < 4; ++ks)
            ot0 = MFMA32(*(const bf16x8*)(Vl + ks * 512 + lane * 8), pa[ks], ot0);
#pragma unroll
        for (int ks = 0; ks < 4; ++ks)
            ot1 = MFMA32(*(const bf16x8*)(Vl + (4 + ks) * 512 + lane * 8), pa[ks], ot1);

        __builtin_amdgcn_s_barrier();             // all waves done reading buf
        if (kb + 2 < 8) STAGE(kb & 1, kb + 2);    // prefetch 2 ahead, same parity
    }
#undef STAGE

    // ---- lane-pair lsum merge (no rescale ever happens; pure sum) ----
    const float lt = lsum + __shfl_xor(lsum, 32);

    // ---- store bf16 partials: d = (r&3)+8*(r>>2)+4*hi ----
    const int row = base + qrow;
    bf16* op = Opart + ((size_t)s * 32768 + row) * 64;
#pragma unroll
    for (int a4 = 0; a4 < 4; ++a4) {
        u32x2 p0, p1;
        p0[0] = cvt_pk_bf16(ot0[a4 * 4 + 0], ot0[a4 * 4 + 1]);
        p0[1] = cvt_pk_bf16(ot0[a4 * 4 + 2], ot0[a4 * 4 + 3]);
        *(u32x2*)(op + a4 * 8 + hi * 4) = p0;
        p1[0] = cvt_pk_bf16(ot1[a4 * 4 + 0], ot1[a4 * 4 + 1]);
        p1[1] = cvt_pk_bf16(ot1[a4 * 4 + 2], ot1[a4 * 4 + 3]);
        *(u32x2*)(op + 32 + a4 * 8 + hi * 4) = p1;
    }
    Ml[(size_t)s * 32768 + row] = lt;             // both hi-lanes write same value
}

// ---------------------------------------------------------------------------
// Kernel 3 (out): FUSED combine + projection + BN + sigmoid-gate.
// O[n][k] = (sum_s Opart_s)*rcp(sum_s l_s) -- plain sum, NaN-incapable.
// [r11-proven verbatim]
// ---------------------------------------------------------------------------
__global__ __launch_bounds__(256) void out_kernel(
    const bf16* __restrict__ Opart, const float* __restrict__ Ml,
    const bf16* __restrict__ Wo, const float* __restrict__ Bo,
    const float* __restrict__ fus, const float* __restrict__ gamma,
    float* __restrict__ out)
{
    const int id = blockIdx.x;
    const int b = id >> 8, nt = id & 255;
    const int t = threadIdx.x, lane = t & 63, w = t >> 6;
    const int l15 = lane & 15, g = lane >> 4;
    const int n = nt * 16 + l15;
    const int cibase = w * 4;

    // per-(n,h) normalization: rl = 1 / sum_s lsum_s
    float rl[2];
#pragma unroll
    for (int h = 0; h < 2; ++h) {
        const int row = (b * 2 + h) * 4096 + n;
        float L = 0.f;
#pragma unroll
        for (int s = 0; s < 8; ++s) L += Ml[(size_t)s * 32768 + row];
        rl[h] = vrcp(L);
    }

    const f32x4 z4 = {0.f, 0.f, 0.f, 0.f};
    f32x4 acc[4] = {z4, z4, z4, z4};
#pragma unroll
    for (int ks = 0; ks < 4; ++ks) {
        const int h = ks >> 1;
        const int row = (b * 2 + h) * 4096 + n;
        const int kk = (ks & 1) * 32 + g * 8;     // d-offset within head
        float fc[8] = {0.f, 0.f, 0.f, 0.f, 0.f, 0.f, 0.f, 0.f};
#pragma unroll
        for (int s = 0; s < 8; ++s) {
            const u32x4 pv = *(const u32x4*)(Opart + ((size_t)s * 32768 + row) * 64 + kk);
#pragma unroll
            for (int pj = 0; pj < 4; ++pj) {
                fc[2 * pj]     += __builtin_bit_cast(float, pv[pj] << 16);
                fc[2 * pj + 1] += __builtin_bit_cast(float, pv[pj] & 0xffff0000u);
            }
        }
        u32x4 pb_;
#pragma unroll
        for (int pj = 0; pj < 4; ++pj)
            pb_[pj] = cvt_pk_bf16(fc[2 * pj] * rl[h], fc[2 * pj + 1] * rl[h]);
        const bf16x8 bfr = __builtin_bit_cast(bf16x8, pb_);
        const int k0 = ks * 32 + g * 8;
#pragma unroll
        for (int ci = 0; ci < 4; ++ci) {
            bf16x8 af = *(const bf16x8*)(Wo + ((cibase + ci) * 16 + l15) * 128 + k0);
            acc[ci] = MFMA16(af, bfr, acc[ci]);
        }
    }
    const float gam = gamma[0];
#pragma unroll
    for (int ci = 0; ci < 4; ++ci) {
        const int c0 = (cibase + ci) * 16 + g * 4;
        const f32x4 bo = *(const f32x4*)(Bo + c0);
#pragma unroll
        for (int r = 0; r < 4; ++r) {
            const int c = c0 + r;
            const size_t off = ((size_t)(b * 256 + c)) * 4096 + n;
            const float v = acc[ci][r] + bo[r];
            const float sg = vrcp(1.0f + vexp2(-v * LOG2E));
            out[off] = fus[off] * fmaf(sg, gam, 1.0f);
        }
    }
}

// ---------------------------------------------------------------------------
extern "C" void kernel_launch(void* const* d_in, const int* in_sizes, int n_in,
                              void* d_out, int out_size, void* d_ws, size_t ws_size,
                              hipStream_t stream)
{
    (void)in_sizes; (void)n_in; (void)out_size; (void)ws_size;
    const float* fusion = (const float*)d_in[0];
    const float* rgb    = (const float*)d_in[1];
    const float* dsm    = (const float*)d_in[2];
    const float* bn1w = (const float*)d_in[3];
    const float* bn1b = (const float*)d_in[4];
    const float* bn1m = (const float*)d_in[5];
    const float* bn1v = (const float*)d_in[6];
    const float* bn2w = (const float*)d_in[7];
    const float* bn2b = (const float*)d_in[8];
    const float* bn2m = (const float*)d_in[9];
    const float* bn2v = (const float*)d_in[10];
    const float* kq1w = (const float*)d_in[11];
    const float* kq1b = (const float*)d_in[12];
    const float* kq2w = (const float*)d_in[13];
    const float* kq2b = (const float*)d_in[14];
    const float* vw   = (const float*)d_in[15];
    const float* vb   = (const float*)d_in[16];
    const float* outw = (const float*)d_in[17];
    const float* outb = (const float*)d_in[18];
    const float* bnlw = (const float*)d_in[19];
    const float* bnlb = (const float*)d_in[20];
    const float* bnlm = (const float*)d_in[21];
    const float* bnlv = (const float*)d_in[22];
    const float* gamma = (const float*)d_in[23];

    char* ws = (char*)d_ws;
    size_t off = 0;
    auto alloc = [&](size_t bytes) { char* p = ws + off; off = (off + bytes + 255) & ~(size_t)255; return p; };
    bf16* Wk1 = (bf16*)alloc(128 * 256 * 2);
    bf16* Wk2 = (bf16*)alloc(128 * 256 * 2);
    bf16* Wv  = (bf16*)alloc(128 * 256 * 2);
    bf16* Wo  = (bf16*)alloc(256 * 128 * 2);
    float* B1 = (float*)alloc(128 * 4);
    float* B2 = (float*)alloc(128 * 4);
    float* Bv = (float*)alloc(128 * 4);
    float* Bo = (float*)alloc(256 * 4);
    bf16* Kp    = (bf16*)alloc((size_t)8 * 64 * 4096 * 2);          // 4 MB
    bf16* Q     = (bf16*)alloc((size_t)8 * 4096 * 64 * 2);          // 4 MB
    bf16* Vp    = (bf16*)alloc((size_t)8 * 64 * 4096 * 2);          // 4 MB
    bf16* Opart = (bf16*)alloc((size_t)8 * 8 * 4096 * 64 * 2);      // 32 MB
    float* Ml   = (float*)alloc((size_t)8 * 8 * 4096 * 4);          // 1 MB

    wprep_kernel<<<640, 64, 0, stream>>>(
        kq1w, kq1b, bn1w, bn1b, bn1m, bn1v,
        kq2w, kq2b, bn2w, bn2b, bn2m, bn2v,
        vw, vb, outw, outb, bnlw, bnlb, bnlm, bnlv,
        Wk1, Wk2, Wv, Wo, B1, B2, Bv, Bo);
    prep_kernel<<<1536, 256, 0, stream>>>(rgb, dsm, fusion,
        Wk1, Wk2, Wv, B1, B2, Bv, Kp, Q, Vp);
    attn_kernel<<<1024, 512, 0, stream>>>(Kp, Q, Vp, Opart, Ml);
    out_kernel<<<1024, 256, 0, stream>>>(Opart, Ml, Wo, Bo, fusion, gamma, (float*)d_out);
}

// Round 13
// 107.036 us; speedup vs baseline: 1.4542x; 1.4542x over previous
//
#include <hip/hip_runtime.h>

typedef __bf16 bf16;
typedef __bf16 bf16x8 __attribute__((ext_vector_type(8)));
typedef float f32x2 __attribute__((ext_vector_type(2)));
typedef float f32x4 __attribute__((ext_vector_type(4)));
typedef float f32x16 __attribute__((ext_vector_type(16)));
typedef unsigned int u32;
typedef u32 u32x2 __attribute__((ext_vector_type(2)));
typedef u32 u32x4 __attribute__((ext_vector_type(4)));

#define MFMA16(A,B,C) __builtin_amdgcn_mfma_f32_16x16x32_bf16(A,B,C,0,0,0)
#define MFMA32(A,B,C) __builtin_amdgcn_mfma_f32_32x32x16_bf16(A,B,C,0,0,0)

#define ALPHA 0.18033688f          /* 0.125 * log2(e): folded into Q          */
#define LOG2E 1.44269504f

static __device__ __forceinline__ u32 cvt_pk_bf16(float lo, float hi) {
    u32 r;
    asm("v_cvt_pk_bf16_f32 %0, %1, %2" : "=v"(r) : "v"(lo), "v"(hi));
    return r;
}
static __device__ __forceinline__ void permlane32_swap(u32& a, u32& b) {
    asm("v_permlane32_swap_b32 %0, %1" : "+v"(a), "+v"(b));
}
// single-instruction 2^x / 1/x (vs libm's multi-inst wrappers); ~1ulp approx.
static __device__ __forceinline__ float vexp2(float x) {
    float r;
    asm("v_exp_f32 %0, %1" : "=v"(r) : "v"(x));
    return r;
}
static __device__ __forceinline__ float vrcp(float x) {
    float r;
    asm("v_rcp_f32 %0, %1" : "=v"(r) : "v"(x));
    return r;
}
// async global->LDS DMA, 16B/lane; LDS dest = uniform base + lane*16 (HW).
static __device__ __forceinline__ void stage16(const bf16* g, bf16* l) {
    __builtin_amdgcn_global_load_lds(
        (const __attribute__((address_space(1))) void*)g,
        (__attribute__((address_space(3))) void*)l, 16, 0, 0);
}

// ---------------------------------------------------------------------------
// Kernel 0 (wprep): fold BN1/BN2 into kq weights+biases, bnl into out_w,
// Q-scale into Q rows; weights -> bf16. [r5-proven verbatim]
// ---------------------------------------------------------------------------
__global__ __launch_bounds__(64) void wprep_kernel(
    const float* __restrict__ kq1w, const float* __restrict__ kq1b,
    const float* __restrict__ bn1w, const float* __restrict__ bn1b,
    const float* __restrict__ bn1m, const float* __restrict__ bn1v,
    const float* __restrict__ kq2w, const float* __restrict__ kq2b,
    const float* __restrict__ bn2w, const float* __restrict__ bn2b,
    const float* __restrict__ bn2m, const float* __restrict__ bn2v,
    const float* __restrict__ vw,   const float* __restrict__ vb,
    const float* __restrict__ outw, const float* __restrict__ outb,
    const float* __restrict__ bnlw, const float* __restrict__ bnlb,
    const float* __restrict__ bnlm, const float* __restrict__ bnlv,
    bf16* __restrict__ Wk1, bf16* __restrict__ Wk2, bf16* __restrict__ Wv,
    bf16* __restrict__ Wo,
    float* __restrict__ B1, float* __restrict__ B2, float* __restrict__ Bv,
    float* __restrict__ Bo)
{
    const int blk = blockIdx.x, lane = threadIdx.x;
    if (blk < 384) {
        const int arr = blk >> 7, j = blk & 127;
        const float* W  = arr == 0 ? kq1w : arr == 1 ? kq2w : vw;
        const float* bs = arr == 0 ? kq1b : arr == 1 ? kq2b : vb;
        bf16*  Wd = arr == 0 ? Wk1 : arr == 1 ? Wk2 : Wv;
        float* Bd = arr == 0 ? B1  : arr == 1 ? B2  : Bv;
        const float scale = (arr < 2 && ((j >> 5) & 1)) ? ALPHA : 1.0f;
        const int c0 = lane * 4;
        f32x4 w4 = *(const f32x4*)(W + j * 256 + c0);
        f32x4 o4; float dot = 0.f;
        if (arr < 2) {
            const float* bw = arr ? bn2w : bn1w;
            const float* bb = arr ? bn2b : bn1b;
            const float* bm = arr ? bn2m : bn1m;
            const float* bv = arr ? bn2v : bn1v;
            f32x4 gw = *(const f32x4*)(bw + c0), gb = *(const f32x4*)(bb + c0);
            f32x4 gm = *(const f32x4*)(bm + c0), gv = *(const f32x4*)(bv + c0);
#pragma unroll
            for (int k = 0; k < 4; ++k) {
                float iv = gw[k] * rsqrtf(gv[k] + 1e-5f);
                float beta = gb[k] - gm[k] * iv;
                o4[k] = w4[k] * iv * scale;
                dot += w4[k] * beta;
            }
        } else {
#pragma unroll
            for (int k = 0; k < 4; ++k) o4[k] = w4[k];
        }
        u32x2 pk; pk[0] = cvt_pk_bf16(o4[0], o4[1]); pk[1] = cvt_pk_bf16(o4[2], o4[3]);
        *(u32x2*)(Wd + j * 256 + c0) = pk;
#pragma unroll
        for (int off = 32; off >= 1; off >>= 1) dot += __shfl_xor(dot, off);
        if (lane == 0) Bd[j] = (bs[j] + dot) * scale;
    } else {
        const int c = blk - 384;
        const float iv = bnlw[c] * rsqrtf(bnlv[c] + 1e-5f);
        const int k0 = lane * 2;
        f32x2 w2 = *(const f32x2*)(outw + c * 128 + k0);
        *(u32*)(Wo + c * 128 + k0) = cvt_pk_bf16(w2[0] * iv, w2[1] * iv);
        if (lane == 0) Bo[c] = outb[c] * iv + bnlb[c] - bnlm[c] * iv;
    }
}

// ---------------------------------------------------------------------------
// Kernel 1 (prep): D[j][n] = W' . X^T  (BN pre-folded). One mode per block.
// NEW vs r11: X tile LDS-staged with coalesced float4 loads (8 f32x4/thread,
// 128B-contiguous per channel row) into sX[256][34] (pad 34 -> fragment-build
// reads 2-way bank-aliased = free). Fragments then built from LDS.
// Fragment-major K/V output layouts [r7-proven] unchanged:
//   Kp[bh][kbg][chunk(512)][8]: chunk = ((kt*4+ds)*2+hi)*32 + l31
//   Vp[bh][kbg][chunk][8]:      chunk = ((dt*4+ks)*2+hi)*32 + (d&31), inner=key&7
// ---------------------------------------------------------------------------
__global__ __launch_bounds__(256) void prep_kernel(
    const float* __restrict__ rgb, const float* __restrict__ dsm,
    const float* __restrict__ fus,
    const bf16* __restrict__ Wk1, const bf16* __restrict__ Wk2,
    const bf16* __restrict__ Wv,
    const float* __restrict__ B1, const float* __restrict__ B2,
    const float* __restrict__ Bv,
    bf16* __restrict__ Kp, bf16* __restrict__ Q, bf16* __restrict__ Vp)
{
    __shared__ float sIv[256], sBt[256];
    __shared__ __align__(16) float sX[256][34];   // pad 34: 2-way read alias (free)

    const int id = blockIdx.x;
    const int mode = id >> 9, sub = id & 511;
    const int b = sub >> 7, nt = sub & 127;
    const int t = threadIdx.x;

    const float* X  = mode == 0 ? rgb : mode == 1 ? dsm : fus;
    const bf16*  W  = mode == 0 ? Wk1 : mode == 1 ? Wk2 : Wv;
    const float* Bs = mode == 0 ? B1  : mode == 1 ? B2  : Bv;

    if (mode == 0) {
        sIv[t] = 1.f; sBt[t] = 0.f;   // overwritten below; keep uniform path
    }
    // BN params (identity for mode 2)
    {
        float iv = 1.f, bt = 0.f;
        (void)iv; (void)bt;
    }
    // Note: BN folding for modes 0/1 was pre-folded into W/B by wprep in r2,
    // but r9/r11 lineage applies BN at fragment build. Here W/B are wprep's
    // FOLDED weights, so X is consumed RAW (wprep folded BN for kq modes).
    // -> no sIv/sBt needed for the GEMM; stage raw X only.

    const float* Xb = X + (size_t)b * 1048576 + (size_t)nt * 32;

    // ---- stage 256c x 32n f32 tile, coalesced float4 ----
#pragma unroll
    for (int i = 0; i < 8; ++i) {
        const int chunk = i * 256 + t;            // 0..2047
        const int c = chunk >> 3, nn4 = (chunk & 7) * 4;
        const f32x4 v4 = *(const f32x4*)(Xb + (size_t)c * 4096 + nn4);
        *(f32x4*)(&sX[c][nn4]) = v4;
    }
    __syncthreads();

    const int lane = t & 63, w = t >> 6;
    const int l15 = lane & 15, g = lane >> 4;
    const int nloc = (w & 1) * 16 + l15;
    const int n = nt * 32 + nloc;
    const int cibase = (w >> 1) * 4;

    const f32x4 z4 = {0.f, 0.f, 0.f, 0.f};
    f32x4 acc[4] = {z4, z4, z4, z4};

#pragma unroll
    for (int ks = 0; ks < 8; ++ks) {
        const int c0 = ks * 32 + g * 8;
        u32x4 xb;
#pragma unroll
        for (int pr = 0; pr < 4; ++pr)
            xb[pr] = cvt_pk_bf16(sX[c0 + 2 * pr][nloc], sX[c0 + 2 * pr + 1][nloc]);
        const bf16x8 bfr = __builtin_bit_cast(bf16x8, xb);
#pragma unroll
        for (int ci = 0; ci < 4; ++ci) {
            bf16x8 af = *(const bf16x8*)(W + ((cibase + ci) * 16 + l15) * 256 + c0);
            acc[ci] = MFMA16(af, bfr, acc[ci]);
        }
    }

#pragma unroll
    for (int ci = 0; ci < 4; ++ci) {
        const int cia = cibase + ci;
        const int j0 = cia * 16 + g * 4;
        const f32x4 bq = *(const f32x4*)(Bs + j0);
        float v0 = acc[ci][0] + bq[0], v1 = acc[ci][1] + bq[1];
        float v2 = acc[ci][2] + bq[2], v3 = acc[ci][3] + bq[3];
        if (mode == 2) {
            const int head = cia >> 2;
            const int bh = b * 2 + head;
            const int dbase = (cia & 3) * 16 + g * 4;
            const int kbg = n >> 6, key = n & 63;
            const int kc = key >> 4, hi2 = (key >> 3) & 1, inner = key & 7;
            bf16* vp = Vp + (size_t)(bh * 64 + kbg) * 4096;
            const float vv[4] = {v0, v1, v2, v3};
#pragma unroll
            for (int rr = 0; rr < 4; ++rr) {
                const int d = dbase + rr;
                const int chunk = (((d >> 5) * 4 + kc) * 2 + hi2) * 32 + (d & 31);
                vp[chunk * 8 + inner] = (bf16)vv[rr];
            }
        } else {
            const int seg = cia >> 1;          // 0:K h0  1:Q h0  2:K h1  3:Q h1
            const int head = seg >> 1;
            const int bh = b * 2 + head;
            const int d0 = (cia & 1) * 16 + g * 4 + (mode == 1 ? 32 : 0);
            u32x2 pk; pk[0] = cvt_pk_bf16(v0, v1); pk[1] = cvt_pk_bf16(v2, v3);
            if (seg & 1) {
                *(u32x2*)(Q + ((size_t)bh * 4096 + n) * 64 + d0) = pk;
            } else {
                const int kbg = n >> 6, r = n & 63;
                const int chunk = (((r >> 5) * 4 + (d0 >> 4)) * 2 + ((d0 >> 3) & 1)) * 32 + (r & 31);
                *(u32x2*)(Kp + (size_t)(bh * 64 + kbg) * 4096 + chunk * 8 + (d0 & 7)) = pk;
            }
        }
    }
}

// ---------------------------------------------------------------------------
// Kernel 2 (attn): split-K x8, LDS-staged K/V, 512-thr/8-wave blocks, m=0
// softmax. [r11-proven verbatim -- r12's counted-vmcnt restructure REVERTED]
// ---------------------------------------------------------------------------
__global__ __launch_bounds__(512) void attn_kernel(
    const bf16* __restrict__ Kp, const bf16* __restrict__ Q,
    const bf16* __restrict__ Vp,
    bf16* __restrict__ Opart, float* __restrict__ Ml)
{
    __shared__ __align__(16) bf16 sK[2][4096];
    __shared__ __align__(16) bf16 sV[2][4096];

    const int id = blockIdx.x;                    // 1024
    const int bh = id & 7;                        // XCD-local
    const int qt = (id >> 3) & 15;
    const int s  = id >> 7;                       // 0..7

    const int t = threadIdx.x, lane = t & 63, w = t >> 6;   // w in 0..7
    const int l31 = lane & 31, hi = lane >> 5;
    const int qrow = qt * 256 + w * 32 + l31;
    const int base = bh * 4096;

    bf16x8 qf[4];
    {
        const bf16* qp = Q + ((size_t)(base + qrow)) * 64 + hi * 8;
#pragma unroll
        for (int ds = 0; ds < 4; ++ds) qf[ds] = *(const bf16x8*)(qp + ds * 16);
    }

    f32x16 ot0, ot1;
#pragma unroll
    for (int i = 0; i < 16; ++i) { ot0[i] = 0.f; ot1[i] = 0.f; }
    float lsum = 0.f;

    const bf16* Kblk = Kp + (size_t)(bh * 64 + s * 8) * 4096;
    const bf16* Vblk = Vp + (size_t)(bh * 64 + s * 8) * 4096;
    const int wo = w * 512 + lane * 8;            // covers 4096 elems over 8 waves

#define STAGE(BUF, KBI)                                                      \
    {                                                                        \
        const size_t gb = (size_t)(KBI) * 4096 + wo;                         \
        stage16(Kblk + gb, &sK[BUF][w * 512]);                               \
        stage16(Vblk + gb, &sV[BUF][w * 512]);                               \
    }

    STAGE(0, 0);
    __syncthreads();
    int buf = 0;

    for (int kb = 0; kb < 8; ++kb) {
        if (kb + 1 < 8) {
            if (buf) STAGE(0, kb + 1) else STAGE(1, kb + 1);
        }
        const bf16* Kl = &sK[buf][0];
        const bf16* Vl = &sV[buf][0];

        // ---- per kt: QK^T -> exp2 on accumulator -> sum -> bf16 frags ----
        bf16x8 pa[4];
#pragma unroll
        for (int kt = 0; kt < 2; ++kt) {
            f32x16 a;
#pragma unroll
            for (int i = 0; i < 16; ++i) a[i] = 0.f;
#pragma unroll
            for (int ds = 0; ds < 4; ++ds)
                a = MFMA32(*(const bf16x8*)(Kl + (kt * 4 + ds) * 512 + lane * 8), qf[ds], a);
#pragma unroll
            for (int r = 0; r < 16; ++r) a[r] = vexp2(a[r]);
            lsum += (((a[0] + a[1]) + (a[2] + a[3])) +
                     ((a[4] + a[5]) + (a[6] + a[7]))) +
                    (((a[8] + a[9]) + (a[10] + a[11])) +
                     ((a[12] + a[13]) + (a[14] + a[15])));
            u32 wa0 = cvt_pk_bf16(a[0], a[1]);
            u32 wa1 = cvt_pk_bf16(a[2], a[3]);
            u32 wb0 = cvt_pk_bf16(a[4], a[5]);
            u32 wb1 = cvt_pk_bf16(a[6], a[7]);
            permlane32_swap(wa0, wb0);
            permlane32_swap(wa1, wb1);
            u32x4 pk0; pk0[0] = wa0; pk0[1] = wa1; pk0[2] = wb0; pk0[3] = wb1;
            pa[2 * kt] = __builtin_bit_cast(bf16x8, pk0);
            u32 wc0 = cvt_pk_bf16(a[8], a[9]);
            u32 wc1 = cvt_pk_bf16(a[10], a[11]);
            u32 wd0 = cvt_pk_bf16(a[12], a[13]);
            u32 wd1 = cvt_pk_bf16(a[14], a[15]);
            permlane32_swap(wc0, wd0);
            permlane32_swap(wc1, wd1);
            u32x4 pk1; pk1[0] = wc0; pk1[1] = wc1; pk1[2] = wd0; pk1[3] = wd1;
            pa[2 * kt + 1] = __builtin_bit_cast(bf16x8, pk1);
        }
        // ---- O^T += V^T . P  (frag i=dt*4+ks) ----
#pragma unroll
        for (int ks = 0; ks < 4; ++ks)
            ot0 = MFMA32(*(const bf16x8*)(Vl + ks * 512 + lane * 8), pa[ks], ot0);
#pragma unroll
        for (int ks = 0; ks < 4; ++ks)
            ot1 = MFMA32(*(const bf16x8*)(Vl + (4 + ks) * 512 + lane * 8), pa[ks], ot1);
        __syncthreads();
        buf ^= 1;
    }
#undef STAGE

    // ---- lane-pair lsum merge (no rescale ever happens; pure sum) ----
    const float lt = lsum + __shfl_xor(lsum, 32);

    // ---- store bf16 partials: d = (r&3)+8*(r>>2)+4*hi ----
    const int row = base + qrow;
    bf16* op = Opart + ((size_t)s * 32768 + row) * 64;
#pragma unroll
    for (int a4 = 0; a4 < 4; ++a4) {
        u32x2 p0, p1;
        p0[0] = cvt_pk_bf16(ot0[a4 * 4 + 0], ot0[a4 * 4 + 1]);
        p0[1] = cvt_pk_bf16(ot0[a4 * 4 + 2], ot0[a4 * 4 + 3]);
        *(u32x2*)(op + a4 * 8 + hi * 4) = p0;
        p1[0] = cvt_pk_bf16(ot1[a4 * 4 + 0], ot1[a4 * 4 + 1]);
        p1[1] = cvt_pk_bf16(ot1[a4 * 4 + 2], ot1[a4 * 4 + 3]);
        *(u32x2*)(op + 32 + a4 * 8 + hi * 4) = p1;
    }
    Ml[(size_t)s * 32768 + row] = lt;             // both hi-lanes write same value
}

// ---------------------------------------------------------------------------
// Kernel 3 (out): FUSED combine + projection + BN + sigmoid-gate.
// O[n][k] = (sum_s Opart_s)*rcp(sum_s l_s) -- plain sum, NaN-incapable.
// [r11-proven verbatim]
// ---------------------------------------------------------------------------
__global__ __launch_bounds__(256) void out_kernel(
    const bf16* __restrict__ Opart, const float* __restrict__ Ml,
    const bf16* __restrict__ Wo, const float* __restrict__ Bo,
    const float* __restrict__ fus, const float* __restrict__ gamma,
    float* __restrict__ out)
{
    const int id = blockIdx.x;
    const int b = id >> 8, nt = id & 255;
    const int t = threadIdx.x, lane = t & 63, w = t >> 6;
    const int l15 = lane & 15, g = lane >> 4;
    const int n = nt * 16 + l15;
    const int cibase = w * 4;

    // per-(n,h) normalization: rl = 1 / sum_s lsum_s
    float rl[2];
#pragma unroll
    for (int h = 0; h < 2; ++h) {
        const int row = (b * 2 + h) * 4096 + n;
        float L = 0.f;
#pragma unroll
        for (int s = 0; s < 8; ++s) L += Ml[(size_t)s * 32768 + row];
        rl[h] = vrcp(L);
    }

    const f32x4 z4 = {0.f, 0.f, 0.f, 0.f};
    f32x4 acc[4] = {z4, z4, z4, z4};
#pragma unroll
    for (int ks = 0; ks < 4; ++ks) {
        const int h = ks >> 1;
        const int row = (b * 2 + h) * 4096 + n;
        const int kk = (ks & 1) * 32 + g * 8;     // d-offset within head
        float fc[8] = {0.f, 0.f, 0.f, 0.f, 0.f, 0.f, 0.f, 0.f};
#pragma unroll
        for (int s = 0; s < 8; ++s) {
            const u32x4 pv = *(const u32x4*)(Opart + ((size_t)s * 32768 + row) * 64 + kk);
#pragma unroll
            for (int pj = 0; pj < 4; ++pj) {
                fc[2 * pj]     += __builtin_bit_cast(float, pv[pj] << 16);
                fc[2 * pj + 1] += __builtin_bit_cast(float, pv[pj] & 0xffff0000u);
            }
        }
        u32x4 pb_;
#pragma unroll
        for (int pj = 0; pj < 4; ++pj)
            pb_[pj] = cvt_pk_bf16(fc[2 * pj] * rl[h], fc[2 * pj + 1] * rl[h]);
        const bf16x8 bfr = __builtin_bit_cast(bf16x8, pb_);
        const int k0 = ks * 32 + g * 8;
#pragma unroll
        for (int ci = 0; ci < 4; ++ci) {
            bf16x8 af = *(const bf16x8*)(Wo + ((cibase + ci) * 16 + l15) * 128 + k0);
            acc[ci] = MFMA16(af, bfr, acc[ci]);
        }
    }
    const float gam = gamma[0];
#pragma unroll
    for (int ci = 0; ci < 4; ++ci) {
        const int c0 = (cibase + ci) * 16 + g * 4;
        const f32x4 bo = *(const f32x4*)(Bo + c0);
#pragma unroll
        for (int r = 0; r < 4; ++r) {
            const int c = c0 + r;
            const size_t off = ((size_t)(b * 256 + c)) * 4096 + n;
            const float v = acc[ci][r] + bo[r];
            const float sg = vrcp(1.0f + vexp2(-v * LOG2E));
            out[off] = fus[off] * fmaf(sg, gam, 1.0f);
        }
    }
}

// ---------------------------------------------------------------------------
extern "C" void kernel_launch(void* const* d_in, const int* in_sizes, int n_in,
                              void* d_out, int out_size, void* d_ws, size_t ws_size,
                              hipStream_t stream)
{
    (void)in_sizes; (void)n_in; (void)out_size; (void)ws_size;
    const float* fusion = (const float*)d_in[0];
    const float* rgb    = (const float*)d_in[1];
    const float* dsm    = (const float*)d_in[2];
    const float* bn1w = (const float*)d_in[3];
    const float* bn1b = (const float*)d_in[4];
    const float* bn1m = (const float*)d_in[5];
    const float* bn1v = (const float*)d_in[6];
    const float* bn2w = (const float*)d_in[7];
    const float* bn2b = (const float*)d_in[8];
    const float* bn2m = (const float*)d_in[9];
    const float* bn2v = (const float*)d_in[10];
    const float* kq1w = (const float*)d_in[11];
    const float* kq1b = (const float*)d_in[12];
    const float* kq2w = (const float*)d_in[13];
    const float* kq2b = (const float*)d_in[14];
    const float* vw   = (const float*)d_in[15];
    const float* vb   = (const float*)d_in[16];
    const float* outw = (const float*)d_in[17];
    const float* outb = (const float*)d_in[18];
    const float* bnlw = (const float*)d_in[19];
    const float* bnlb = (const float*)d_in[20];
    const float* bnlm = (const float*)d_in[21];
    const float* bnlv = (const float*)d_in[22];
    const float* gamma = (const float*)d_in[23];

    char* ws = (char*)d_ws;
    size_t off = 0;
    auto alloc = [&](size_t bytes) { char* p = ws + off; off = (off + bytes + 255) & ~(size_t)255; return p; };
    bf16* Wk1 = (bf16*)alloc(128 * 256 * 2);
    bf16* Wk2 = (bf16*)alloc(128 * 256 * 2);
    bf16* Wv  = (bf16*)alloc(128 * 256 * 2);
    bf16* Wo  = (bf16*)alloc(256 * 128 * 2);
    float* B1 = (float*)alloc(128 * 4);
    float* B2 = (float*)alloc(128 * 4);
    float* Bv = (float*)alloc(128 * 4);
    float* Bo = (float*)alloc(256 * 4);
    bf16* Kp    = (bf16*)alloc((size_t)8 * 64 * 4096 * 2);          // 4 MB
    bf16* Q     = (bf16*)alloc((size_t)8 * 4096 * 64 * 2);          // 4 MB
    bf16* Vp    = (bf16*)alloc((size_t)8 * 64 * 4096 * 2);          // 4 MB
    bf16* Opart = (bf16*)alloc((size_t)8 * 8 * 4096 * 64 * 2);      // 32 MB
    float* Ml   = (float*)alloc((size_t)8 * 8 * 4096 * 4);          // 1 MB

    wprep_kernel<<<640, 64, 0, stream>>>(
        kq1w, kq1b, bn1w, bn1b, bn1m, bn1v,
        kq2w, kq2b, bn2w, bn2b, bn2m, bn2v,
        vw, vb, outw, outb, bnlw, bnlb, bnlm, bnlv,
        Wk1, Wk2, Wv, Wo, B1, B2, Bv, Bo);
    prep_kernel<<<1536, 256, 0, stream>>>(rgb, dsm, fusion,
        Wk1, Wk2, Wv, B1, B2, Bv, Kp, Q, Vp);
    attn_kernel<<<1024, 512, 0, stream>>>(Kp, Q, Vp, Opart, Ml);
    out_kernel<<<1024, 256, 0, stream>>>(Opart, Ml, Wo, Bo, fusion, gamma, (float*)d_out);
}

// Round 14
// 96.998 us; speedup vs baseline: 1.6047x; 1.1035x over previous
//
#include <hip/hip_runtime.h>

typedef __bf16 bf16;
typedef __bf16 bf16x8 __attribute__((ext_vector_type(8)));
typedef float f32x2 __attribute__((ext_vector_type(2)));
typedef float f32x4 __attribute__((ext_vector_type(4)));
typedef float f32x16 __attribute__((ext_vector_type(16)));
typedef unsigned int u32;
typedef u32 u32x2 __attribute__((ext_vector_type(2)));
typedef u32 u32x4 __attribute__((ext_vector_type(4)));

#define MFMA16(A,B,C) __builtin_amdgcn_mfma_f32_16x16x32_bf16(A,B,C,0,0,0)
#define MFMA32(A,B,C) __builtin_amdgcn_mfma_f32_32x32x16_bf16(A,B,C,0,0,0)

#define ALPHA 0.18033688f          /* 0.125 * log2(e): folded into Q          */
#define LOG2E 1.44269504f

static __device__ __forceinline__ u32 cvt_pk_bf16(float lo, float hi) {
    u32 r;
    asm("v_cvt_pk_bf16_f32 %0, %1, %2" : "=v"(r) : "v"(lo), "v"(hi));
    return r;
}
static __device__ __forceinline__ void permlane32_swap(u32& a, u32& b) {
    asm("v_permlane32_swap_b32 %0, %1" : "+v"(a), "+v"(b));
}
// single-instruction 2^x / 1/x (vs libm's multi-inst wrappers); ~1ulp approx.
static __device__ __forceinline__ float vexp2(float x) {
    float r;
    asm("v_exp_f32 %0, %1" : "=v"(r) : "v"(x));
    return r;
}
static __device__ __forceinline__ float vrcp(float x) {
    float r;
    asm("v_rcp_f32 %0, %1" : "=v"(r) : "v"(x));
    return r;
}
// async global->LDS DMA, 16B/lane; LDS dest = uniform base + lane*16 (HW).
static __device__ __forceinline__ void stage16(const bf16* g, bf16* l) {
    __builtin_amdgcn_global_load_lds(
        (const __attribute__((address_space(1))) void*)g,
        (__attribute__((address_space(3))) void*)l, 16, 0, 0);
}

// ---------------------------------------------------------------------------
// Kernel 0 (wprep): fold BN1/BN2 into kq weights+biases, bnl into out_w,
// Q-scale into Q rows; weights -> bf16. [r5-proven verbatim]
// ---------------------------------------------------------------------------
__global__ __launch_bounds__(64) void wprep_kernel(
    const float* __restrict__ kq1w, const float* __restrict__ kq1b,
    const float* __restrict__ bn1w, const float* __restrict__ bn1b,
    const float* __restrict__ bn1m, const float* __restrict__ bn1v,
    const float* __restrict__ kq2w, const float* __restrict__ kq2b,
    const float* __restrict__ bn2w, const float* __restrict__ bn2b,
    const float* __restrict__ bn2m, const float* __restrict__ bn2v,
    const float* __restrict__ vw,   const float* __restrict__ vb,
    const float* __restrict__ outw, const float* __restrict__ outb,
    const float* __restrict__ bnlw, const float* __restrict__ bnlb,
    const float* __restrict__ bnlm, const float* __restrict__ bnlv,
    bf16* __restrict__ Wk1, bf16* __restrict__ Wk2, bf16* __restrict__ Wv,
    bf16* __restrict__ Wo,
    float* __restrict__ B1, float* __restrict__ B2, float* __restrict__ Bv,
    float* __restrict__ Bo)
{
    const int blk = blockIdx.x, lane = threadIdx.x;
    if (blk < 384) {
        const int arr = blk >> 7, j = blk & 127;
        const float* W  = arr == 0 ? kq1w : arr == 1 ? kq2w : vw;
        const float* bs = arr == 0 ? kq1b : arr == 1 ? kq2b : vb;
        bf16*  Wd = arr == 0 ? Wk1 : arr == 1 ? Wk2 : Wv;
        float* Bd = arr == 0 ? B1  : arr == 1 ? B2  : Bv;
        const float scale = (arr < 2 && ((j >> 5) & 1)) ? ALPHA : 1.0f;
        const int c0 = lane * 4;
        f32x4 w4 = *(const f32x4*)(W + j * 256 + c0);
        f32x4 o4; float dot = 0.f;
        if (arr < 2) {
            const float* bw = arr ? bn2w : bn1w;
            const float* bb = arr ? bn2b : bn1b;
            const float* bm = arr ? bn2m : bn1m;
            const float* bv = arr ? bn2v : bn1v;
            f32x4 gw = *(const f32x4*)(bw + c0), gb = *(const f32x4*)(bb + c0);
            f32x4 gm = *(const f32x4*)(bm + c0), gv = *(const f32x4*)(bv + c0);
#pragma unroll
            for (int k = 0; k < 4; ++k) {
                float iv = gw[k] * rsqrtf(gv[k] + 1e-5f);
                float beta = gb[k] - gm[k] * iv;
                o4[k] = w4[k] * iv * scale;
                dot += w4[k] * beta;
            }
        } else {
#pragma unroll
            for (int k = 0; k < 4; ++k) o4[k] = w4[k];
        }
        u32x2 pk; pk[0] = cvt_pk_bf16(o4[0], o4[1]); pk[1] = cvt_pk_bf16(o4[2], o4[3]);
        *(u32x2*)(Wd + j * 256 + c0) = pk;
#pragma unroll
        for (int off = 32; off >= 1; off >>= 1) dot += __shfl_xor(dot, off);
        if (lane == 0) Bd[j] = (bs[j] + dot) * scale;
    } else {
        const int c = blk - 384;
        const float iv = bnlw[c] * rsqrtf(bnlv[c] + 1e-5f);
        const int k0 = lane * 2;
        f32x2 w2 = *(const f32x2*)(outw + c * 128 + k0);
        *(u32*)(Wo + c * 128 + k0) = cvt_pk_bf16(w2[0] * iv, w2[1] * iv);
        if (lane == 0) Bo[c] = outb[c] * iv + bnlb[c] - bnlm[c] * iv;
    }
}

// ---------------------------------------------------------------------------
// Kernel 1 (prep): D[j][n] = W' . X^T  (BN pre-folded into W/B by wprep).
// One mode per block; X tile LDS-staged with coalesced float4 loads.
// Fragment-major K/V output layouts [r7-proven]:
//   Kp[bh][kbg][chunk(512)][8]: chunk = ((kt*4+ds)*2+hi)*32 + l31
//   Vp[bh][kbg][chunk][8]:      chunk = ((dt*4+ks)*2+hi)*32 + (d&31), inner=key&7
// [r13-proven verbatim]
// ---------------------------------------------------------------------------
__global__ __launch_bounds__(256) void prep_kernel(
    const float* __restrict__ rgb, const float* __restrict__ dsm,
    const float* __restrict__ fus,
    const bf16* __restrict__ Wk1, const bf16* __restrict__ Wk2,
    const bf16* __restrict__ Wv,
    const float* __restrict__ B1, const float* __restrict__ B2,
    const float* __restrict__ Bv,
    bf16* __restrict__ Kp, bf16* __restrict__ Q, bf16* __restrict__ Vp)
{
    __shared__ __align__(16) float sX[256][34];   // pad 34: 2-way read alias (free)

    const int id = blockIdx.x;
    const int mode = id >> 9, sub = id & 511;
    const int b = sub >> 7, nt = sub & 127;
    const int t = threadIdx.x;

    const float* X  = mode == 0 ? rgb : mode == 1 ? dsm : fus;
    const bf16*  W  = mode == 0 ? Wk1 : mode == 1 ? Wk2 : Wv;
    const float* Bs = mode == 0 ? B1  : mode == 1 ? B2  : Bv;

    const float* Xb = X + (size_t)b * 1048576 + (size_t)nt * 32;

    // ---- stage 256c x 32n f32 tile, coalesced float4 ----
#pragma unroll
    for (int i = 0; i < 8; ++i) {
        const int chunk = i * 256 + t;            // 0..2047
        const int c = chunk >> 3, nn4 = (chunk & 7) * 4;
        const f32x4 v4 = *(const f32x4*)(Xb + (size_t)c * 4096 + nn4);
        *(f32x4*)(&sX[c][nn4]) = v4;
    }
    __syncthreads();

    const int lane = t & 63, w = t >> 6;
    const int l15 = lane & 15, g = lane >> 4;
    const int nloc = (w & 1) * 16 + l15;
    const int n = nt * 32 + nloc;
    const int cibase = (w >> 1) * 4;

    const f32x4 z4 = {0.f, 0.f, 0.f, 0.f};
    f32x4 acc[4] = {z4, z4, z4, z4};

#pragma unroll
    for (int ks = 0; ks < 8; ++ks) {
        const int c0 = ks * 32 + g * 8;
        u32x4 xb;
#pragma unroll
        for (int pr = 0; pr < 4; ++pr)
            xb[pr] = cvt_pk_bf16(sX[c0 + 2 * pr][nloc], sX[c0 + 2 * pr + 1][nloc]);
        const bf16x8 bfr = __builtin_bit_cast(bf16x8, xb);
#pragma unroll
        for (int ci = 0; ci < 4; ++ci) {
            bf16x8 af = *(const bf16x8*)(W + ((cibase + ci) * 16 + l15) * 256 + c0);
            acc[ci] = MFMA16(af, bfr, acc[ci]);
        }
    }

#pragma unroll
    for (int ci = 0; ci < 4; ++ci) {
        const int cia = cibase + ci;
        const int j0 = cia * 16 + g * 4;
        const f32x4 bq = *(const f32x4*)(Bs + j0);
        float v0 = acc[ci][0] + bq[0], v1 = acc[ci][1] + bq[1];
        float v2 = acc[ci][2] + bq[2], v3 = acc[ci][3] + bq[3];
        if (mode == 2) {
            const int head = cia >> 2;
            const int bh = b * 2 + head;
            const int dbase = (cia & 3) * 16 + g * 4;
            const int kbg = n >> 6, key = n & 63;
            const int kc = key >> 4, hi2 = (key >> 3) & 1, inner = key & 7;
            bf16* vp = Vp + (size_t)(bh * 64 + kbg) * 4096;
            const float vv[4] = {v0, v1, v2, v3};
#pragma unroll
            for (int rr = 0; rr < 4; ++rr) {
                const int d = dbase + rr;
                const int chunk = (((d >> 5) * 4 + kc) * 2 + hi2) * 32 + (d & 31);
                vp[chunk * 8 + inner] = (bf16)vv[rr];
            }
        } else {
            const int seg = cia >> 1;          // 0:K h0  1:Q h0  2:K h1  3:Q h1
            const int head = seg >> 1;
            const int bh = b * 2 + head;
            const int d0 = (cia & 1) * 16 + g * 4 + (mode == 1 ? 32 : 0);
            u32x2 pk; pk[0] = cvt_pk_bf16(v0, v1); pk[1] = cvt_pk_bf16(v2, v3);
            if (seg & 1) {
                *(u32x2*)(Q + ((size_t)bh * 4096 + n) * 64 + d0) = pk;
            } else {
                const int kbg = n >> 6, r = n & 63;
                const int chunk = (((r >> 5) * 4 + (d0 >> 4)) * 2 + ((d0 >> 3) & 1)) * 32 + (r & 31);
                *(u32x2*)(Kp + (size_t)(bh * 64 + kbg) * 4096 + chunk * 8 + (d0 & 7)) = pk;
            }
        }
    }
}

// ---------------------------------------------------------------------------
// Kernel 2 (attn): split-K x4 (was x8), LDS-staged K/V, 512-thr/8-wave
// blocks, m=0 softmax. [r11/r13-proven body; only split-count/grid changed:
// grid 512 = bh(id&7) x qt((id>>3)&15) x s(id>>7, 0..3); 16 kb per block.]
// Halves Opart traffic (33.8 -> ~17 MB each way).
// ---------------------------------------------------------------------------
__global__ __launch_bounds__(512) void attn_kernel(
    const bf16* __restrict__ Kp, const bf16* __restrict__ Q,
    const bf16* __restrict__ Vp,
    bf16* __restrict__ Opart, float* __restrict__ Ml)
{
    __shared__ __align__(16) bf16 sK[2][4096];
    __shared__ __align__(16) bf16 sV[2][4096];

    const int id = blockIdx.x;                    // 512
    const int bh = id & 7;                        // XCD-local
    const int qt = (id >> 3) & 15;
    const int s  = id >> 7;                       // 0..3

    const int t = threadIdx.x, lane = t & 63, w = t >> 6;   // w in 0..7
    const int l31 = lane & 31, hi = lane >> 5;
    const int qrow = qt * 256 + w * 32 + l31;
    const int base = bh * 4096;

    bf16x8 qf[4];
    {
        const bf16* qp = Q + ((size_t)(base + qrow)) * 64 + hi * 8;
#pragma unroll
        for (int ds = 0; ds < 4; ++ds) qf[ds] = *(const bf16x8*)(qp + ds * 16);
    }

    f32x16 ot0, ot1;
#pragma unroll
    for (int i = 0; i < 16; ++i) { ot0[i] = 0.f; ot1[i] = 0.f; }
    float lsum = 0.f;

    const bf16* Kblk = Kp + (size_t)(bh * 64 + s * 16) * 4096;
    const bf16* Vblk = Vp + (size_t)(bh * 64 + s * 16) * 4096;
    const int wo = w * 512 + lane * 8;            // covers 4096 elems over 8 waves

#define STAGE(BUF, KBI)                                                      \
    {                                                                        \
        const size_t gb = (size_t)(KBI) * 4096 + wo;                         \
        stage16(Kblk + gb, &sK[BUF][w * 512]);                               \
        stage16(Vblk + gb, &sV[BUF][w * 512]);                               \
    }

    STAGE(0, 0);
    __syncthreads();
    int buf = 0;

    for (int kb = 0; kb < 16; ++kb) {
        if (kb + 1 < 16) {
            if (buf) STAGE(0, kb + 1) else STAGE(1, kb + 1);
        }
        const bf16* Kl = &sK[buf][0];
        const bf16* Vl = &sV[buf][0];

        // ---- per kt: QK^T -> exp2 on accumulator -> sum -> bf16 frags ----
        bf16x8 pa[4];
#pragma unroll
        for (int kt = 0; kt < 2; ++kt) {
            f32x16 a;
#pragma unroll
            for (int i = 0; i < 16; ++i) a[i] = 0.f;
#pragma unroll
            for (int ds = 0; ds < 4; ++ds)
                a = MFMA32(*(const bf16x8*)(Kl + (kt * 4 + ds) * 512 + lane * 8), qf[ds], a);
#pragma unroll
            for (int r = 0; r < 16; ++r) a[r] = vexp2(a[r]);
            lsum += (((a[0] + a[1]) + (a[2] + a[3])) +
                     ((a[4] + a[5]) + (a[6] + a[7]))) +
                    (((a[8] + a[9]) + (a[10] + a[11])) +
                     ((a[12] + a[13]) + (a[14] + a[15])));
            u32 wa0 = cvt_pk_bf16(a[0], a[1]);
            u32 wa1 = cvt_pk_bf16(a[2], a[3]);
            u32 wb0 = cvt_pk_bf16(a[4], a[5]);
            u32 wb1 = cvt_pk_bf16(a[6], a[7]);
            permlane32_swap(wa0, wb0);
            permlane32_swap(wa1, wb1);
            u32x4 pk0; pk0[0] = wa0; pk0[1] = wa1; pk0[2] = wb0; pk0[3] = wb1;
            pa[2 * kt] = __builtin_bit_cast(bf16x8, pk0);
            u32 wc0 = cvt_pk_bf16(a[8], a[9]);
            u32 wc1 = cvt_pk_bf16(a[10], a[11]);
            u32 wd0 = cvt_pk_bf16(a[12], a[13]);
            u32 wd1 = cvt_pk_bf16(a[14], a[15]);
            permlane32_swap(wc0, wd0);
            permlane32_swap(wc1, wd1);
            u32x4 pk1; pk1[0] = wc0; pk1[1] = wc1; pk1[2] = wd0; pk1[3] = wd1;
            pa[2 * kt + 1] = __builtin_bit_cast(bf16x8, pk1);
        }
        // ---- O^T += V^T . P  (frag i=dt*4+ks) ----
#pragma unroll
        for (int ks = 0; ks < 4; ++ks)
            ot0 = MFMA32(*(const bf16x8*)(Vl + ks * 512 + lane * 8), pa[ks], ot0);
#pragma unroll
        for (int ks = 0; ks < 4; ++ks)
            ot1 = MFMA32(*(const bf16x8*)(Vl + (4 + ks) * 512 + lane * 8), pa[ks], ot1);
        __syncthreads();
        buf ^= 1;
    }
#undef STAGE

    // ---- lane-pair lsum merge (no rescale ever happens; pure sum) ----
    const float lt = lsum + __shfl_xor(lsum, 32);

    // ---- store bf16 partials: d = (r&3)+8*(r>>2)+4*hi ----
    const int row = base + qrow;
    bf16* op = Opart + ((size_t)s * 32768 + row) * 64;
#pragma unroll
    for (int a4 = 0; a4 < 4; ++a4) {
        u32x2 p0, p1;
        p0[0] = cvt_pk_bf16(ot0[a4 * 4 + 0], ot0[a4 * 4 + 1]);
        p0[1] = cvt_pk_bf16(ot0[a4 * 4 + 2], ot0[a4 * 4 + 3]);
        *(u32x2*)(op + a4 * 8 + hi * 4) = p0;
        p1[0] = cvt_pk_bf16(ot1[a4 * 4 + 0], ot1[a4 * 4 + 1]);
        p1[1] = cvt_pk_bf16(ot1[a4 * 4 + 2], ot1[a4 * 4 + 3]);
        *(u32x2*)(op + 32 + a4 * 8 + hi * 4) = p1;
    }
    Ml[(size_t)s * 32768 + row] = lt;             // both hi-lanes write same value
}

// ---------------------------------------------------------------------------
// Kernel 3 (out): FUSED combine + projection + BN + sigmoid-gate.
// O[n][k] = (sum_s Opart_s)*rcp(sum_s l_s) -- plain sum over 4 splits.
// [r11-proven structure; split count 8 -> 4]
// ---------------------------------------------------------------------------
__global__ __launch_bounds__(256) void out_kernel(
    const bf16* __restrict__ Opart, const float* __restrict__ Ml,
    const bf16* __restrict__ Wo, const float* __restrict__ Bo,
    const float* __restrict__ fus, const float* __restrict__ gamma,
    float* __restrict__ out)
{
    const int id = blockIdx.x;
    const int b = id >> 8, nt = id & 255;
    const int t = threadIdx.x, lane = t & 63, w = t >> 6;
    const int l15 = lane & 15, g = lane >> 4;
    const int n = nt * 16 + l15;
    const int cibase = w * 4;

    // per-(n,h) normalization: rl = 1 / sum_s lsum_s
    float rl[2];
#pragma unroll
    for (int h = 0; h < 2; ++h) {
        const int row = (b * 2 + h) * 4096 + n;
        float L = 0.f;
#pragma unroll
        for (int s = 0; s < 4; ++s) L += Ml[(size_t)s * 32768 + row];
        rl[h] = vrcp(L);
    }

    const f32x4 z4 = {0.f, 0.f, 0.f, 0.f};
    f32x4 acc[4] = {z4, z4, z4, z4};
#pragma unroll
    for (int ks = 0; ks < 4; ++ks) {
        const int h = ks >> 1;
        const int row = (b * 2 + h) * 4096 + n;
        const int kk = (ks & 1) * 32 + g * 8;     // d-offset within head
        float fc[8] = {0.f, 0.f, 0.f, 0.f, 0.f, 0.f, 0.f, 0.f};
#pragma unroll
        for (int s = 0; s < 4; ++s) {
            const u32x4 pv = *(const u32x4*)(Opart + ((size_t)s * 32768 + row) * 64 + kk);
#pragma unroll
            for (int pj = 0; pj < 4; ++pj) {
                fc[2 * pj]     += __builtin_bit_cast(float, pv[pj] << 16);
                fc[2 * pj + 1] += __builtin_bit_cast(float, pv[pj] & 0xffff0000u);
            }
        }
        u32x4 pb_;
#pragma unroll
        for (int pj = 0; pj < 4; ++pj)
            pb_[pj] = cvt_pk_bf16(fc[2 * pj] * rl[h], fc[2 * pj + 1] * rl[h]);
        const bf16x8 bfr = __builtin_bit_cast(bf16x8, pb_);
        const int k0 = ks * 32 + g * 8;
#pragma unroll
        for (int ci = 0; ci < 4; ++ci) {
            bf16x8 af = *(const bf16x8*)(Wo + ((cibase + ci) * 16 + l15) * 128 + k0);
            acc[ci] = MFMA16(af, bfr, acc[ci]);
        }
    }
    const float gam = gamma[0];
#pragma unroll
    for (int ci = 0; ci < 4; ++ci) {
        const int c0 = (cibase + ci) * 16 + g * 4;
        const f32x4 bo = *(const f32x4*)(Bo + c0);
#pragma unroll
        for (int r = 0; r < 4; ++r) {
            const int c = c0 + r;
            const size_t off = ((size_t)(b * 256 + c)) * 4096 + n;
            const float v = acc[ci][r] + bo[r];
            const float sg = vrcp(1.0f + vexp2(-v * LOG2E));
            out[off] = fus[off] * fmaf(sg, gam, 1.0f);
        }
    }
}

// ---------------------------------------------------------------------------
extern "C" void kernel_launch(void* const* d_in, const int* in_sizes, int n_in,
                              void* d_out, int out_size, void* d_ws, size_t ws_size,
                              hipStream_t stream)
{
    (void)in_sizes; (void)n_in; (void)out_size; (void)ws_size;
    const float* fusion = (const float*)d_in[0];
    const float* rgb    = (const float*)d_in[1];
    const float* dsm    = (const float*)d_in[2];
    const float* bn1w = (const float*)d_in[3];
    const float* bn1b = (const float*)d_in[4];
    const float* bn1m = (const float*)d_in[5];
    const float* bn1v = (const float*)d_in[6];
    const float* bn2w = (const float*)d_in[7];
    const float* bn2b = (const float*)d_in[8];
    const float* bn2m = (const float*)d_in[9];
    const float* bn2v = (const float*)d_in[10];
    const float* kq1w = (const float*)d_in[11];
    const float* kq1b = (const float*)d_in[12];
    const float* kq2w = (const float*)d_in[13];
    const float* kq2b = (const float*)d_in[14];
    const float* vw   = (const float*)d_in[15];
    const float* vb   = (const float*)d_in[16];
    const float* outw = (const float*)d_in[17];
    const float* outb = (const float*)d_in[18];
    const float* bnlw = (const float*)d_in[19];
    const float* bnlb = (const float*)d_in[20];
    const float* bnlm = (const float*)d_in[21];
    const float* bnlv = (const float*)d_in[22];
    const float* gamma = (const float*)d_in[23];

    char* ws = (char*)d_ws;
    size_t off = 0;
    auto alloc = [&](size_t bytes) { char* p = ws + off; off = (off + bytes + 255) & ~(size_t)255; return p; };
    bf16* Wk1 = (bf16*)alloc(128 * 256 * 2);
    bf16* Wk2 = (bf16*)alloc(128 * 256 * 2);
    bf16* Wv  = (bf16*)alloc(128 * 256 * 2);
    bf16* Wo  = (bf16*)alloc(256 * 128 * 2);
    float* B1 = (float*)alloc(128 * 4);
    float* B2 = (float*)alloc(128 * 4);
    float* Bv = (float*)alloc(128 * 4);
    float* Bo = (float*)alloc(256 * 4);
    bf16* Kp    = (bf16*)alloc((size_t)8 * 64 * 4096 * 2);          // 4 MB
    bf16* Q     = (bf16*)alloc((size_t)8 * 4096 * 64 * 2);          // 4 MB
    bf16* Vp    = (bf16*)alloc((size_t)8 * 64 * 4096 * 2);          // 4 MB
    bf16* Opart = (bf16*)alloc((size_t)4 * 8 * 4096 * 64 * 2);      // 16 MB
    float* Ml   = (float*)alloc((size_t)4 * 8 * 4096 * 4);          // 0.5 MB

    wprep_kernel<<<640, 64, 0, stream>>>(
        kq1w, kq1b, bn1w, bn1b, bn1m, bn1v,
        kq2w, kq2b, bn2w, bn2b, bn2m, bn2v,
        vw, vb, outw, outb, bnlw, bnlb, bnlm, bnlv,
        Wk1, Wk2, Wv, Wo, B1, B2, Bv, Bo);
    prep_kernel<<<1536, 256, 0, stream>>>(rgb, dsm, fusion,
        Wk1, Wk2, Wv, B1, B2, Bv, Kp, Q, Vp);
    attn_kernel<<<512, 512, 0, stream>>>(Kp, Q, Vp, Opart, Ml);
    out_kernel<<<1024, 256, 0, stream>>>(Opart, Ml, Wo, Bo, fusion, gamma, (float*)d_out);
}

// Round 15
// 94.580 us; speedup vs baseline: 1.6457x; 1.0256x over previous
//
#include <hip/hip_runtime.h>

typedef __bf16 bf16;
typedef __bf16 bf16x8 __attribute__((ext_vector_type(8)));
typedef float f32x2 __attribute__((ext_vector_type(2)));
typedef float f32x4 __attribute__((ext_vector_type(4)));
typedef float f32x16 __attribute__((ext_vector_type(16)));
typedef unsigned int u32;
typedef u32 u32x2 __attribute__((ext_vector_type(2)));
typedef u32 u32x4 __attribute__((ext_vector_type(4)));

#define MFMA16(A,B,C) __builtin_amdgcn_mfma_f32_16x16x32_bf16(A,B,C,0,0,0)
#define MFMA32(A,B,C) __builtin_amdgcn_mfma_f32_32x32x16_bf16(A,B,C,0,0,0)

#define ALPHA 0.18033688f          /* 0.125 * log2(e): folded into Q          */
#define LOG2E 1.44269504f

static __device__ __forceinline__ u32 cvt_pk_bf16(float lo, float hi) {
    u32 r;
    asm("v_cvt_pk_bf16_f32 %0, %1, %2" : "=v"(r) : "v"(lo), "v"(hi));
    return r;
}
static __device__ __forceinline__ void permlane32_swap(u32& a, u32& b) {
    asm("v_permlane32_swap_b32 %0, %1" : "+v"(a), "+v"(b));
}
// single-instruction 2^x / 1/x (vs libm's multi-inst wrappers); ~1ulp approx.
static __device__ __forceinline__ float vexp2(float x) {
    float r;
    asm("v_exp_f32 %0, %1" : "=v"(r) : "v"(x));
    return r;
}
static __device__ __forceinline__ float vrcp(float x) {
    float r;
    asm("v_rcp_f32 %0, %1" : "=v"(r) : "v"(x));
    return r;
}
// async global->LDS DMA, 16B/lane; LDS dest = uniform base + lane*16 (HW).
static __device__ __forceinline__ void stage16(const bf16* g, bf16* l) {
    __builtin_amdgcn_global_load_lds(
        (const __attribute__((address_space(1))) void*)g,
        (__attribute__((address_space(3))) void*)l, 16, 0, 0);
}

// ---------------------------------------------------------------------------
// Kernel 0 (wprep): fold BN1/BN2 into kq weights+biases, bnl into out_w,
// Q-scale into Q rows; weights -> bf16. [r5-proven verbatim]
// ---------------------------------------------------------------------------
__global__ __launch_bounds__(64) void wprep_kernel(
    const float* __restrict__ kq1w, const float* __restrict__ kq1b,
    const float* __restrict__ bn1w, const float* __restrict__ bn1b,
    const float* __restrict__ bn1m, const float* __restrict__ bn1v,
    const float* __restrict__ kq2w, const float* __restrict__ kq2b,
    const float* __restrict__ bn2w, const float* __restrict__ bn2b,
    const float* __restrict__ bn2m, const float* __restrict__ bn2v,
    const float* __restrict__ vw,   const float* __restrict__ vb,
    const float* __restrict__ outw, const float* __restrict__ outb,
    const float* __restrict__ bnlw, const float* __restrict__ bnlb,
    const float* __restrict__ bnlm, const float* __restrict__ bnlv,
    bf16* __restrict__ Wk1, bf16* __restrict__ Wk2, bf16* __restrict__ Wv,
    bf16* __restrict__ Wo,
    float* __restrict__ B1, float* __restrict__ B2, float* __restrict__ Bv,
    float* __restrict__ Bo)
{
    const int blk = blockIdx.x, lane = threadIdx.x;
    if (blk < 384) {
        const int arr = blk >> 7, j = blk & 127;
        const float* W  = arr == 0 ? kq1w : arr == 1 ? kq2w : vw;
        const float* bs = arr == 0 ? kq1b : arr == 1 ? kq2b : vb;
        bf16*  Wd = arr == 0 ? Wk1 : arr == 1 ? Wk2 : Wv;
        float* Bd = arr == 0 ? B1  : arr == 1 ? B2  : Bv;
        const float scale = (arr < 2 && ((j >> 5) & 1)) ? ALPHA : 1.0f;
        const int c0 = lane * 4;
        f32x4 w4 = *(const f32x4*)(W + j * 256 + c0);
        f32x4 o4; float dot = 0.f;
        if (arr < 2) {
            const float* bw = arr ? bn2w : bn1w;
            const float* bb = arr ? bn2b : bn1b;
            const float* bm = arr ? bn2m : bn1m;
            const float* bv = arr ? bn2v : bn1v;
            f32x4 gw = *(const f32x4*)(bw + c0), gb = *(const f32x4*)(bb + c0);
            f32x4 gm = *(const f32x4*)(bm + c0), gv = *(const f32x4*)(bv + c0);
#pragma unroll
            for (int k = 0; k < 4; ++k) {
                float iv = gw[k] * rsqrtf(gv[k] + 1e-5f);
                float beta = gb[k] - gm[k] * iv;
                o4[k] = w4[k] * iv * scale;
                dot += w4[k] * beta;
            }
        } else {
#pragma unroll
            for (int k = 0; k < 4; ++k) o4[k] = w4[k];
        }
        u32x2 pk; pk[0] = cvt_pk_bf16(o4[0], o4[1]); pk[1] = cvt_pk_bf16(o4[2], o4[3]);
        *(u32x2*)(Wd + j * 256 + c0) = pk;
#pragma unroll
        for (int off = 32; off >= 1; off >>= 1) dot += __shfl_xor(dot, off);
        if (lane == 0) Bd[j] = (bs[j] + dot) * scale;
    } else {
        const int c = blk - 384;
        const float iv = bnlw[c] * rsqrtf(bnlv[c] + 1e-5f);
        const int k0 = lane * 2;
        f32x2 w2 = *(const f32x2*)(outw + c * 128 + k0);
        *(u32*)(Wo + c * 128 + k0) = cvt_pk_bf16(w2[0] * iv, w2[1] * iv);
        if (lane == 0) Bo[c] = outb[c] * iv + bnlb[c] - bnlm[c] * iv;
    }
}

// ---------------------------------------------------------------------------
// Kernel 1 (prep): D[j][n] = W' . X^T  (BN pre-folded into W/B by wprep).
// One mode per block; X tile LDS-staged with coalesced float4 loads.
// Fragment-major K/V output layouts [r7-proven]:
//   Kp[bh][kbg][chunk(512)][8]: chunk = ((kt*4+ds)*2+hi)*32 + l31
//   Vp[bh][kbg][chunk][8]:      chunk = ((dt*4+ks)*2+hi)*32 + (d&31), inner=key&7
// [r13-proven verbatim]
// ---------------------------------------------------------------------------
__global__ __launch_bounds__(256) void prep_kernel(
    const float* __restrict__ rgb, const float* __restrict__ dsm,
    const float* __restrict__ fus,
    const bf16* __restrict__ Wk1, const bf16* __restrict__ Wk2,
    const bf16* __restrict__ Wv,
    const float* __restrict__ B1, const float* __restrict__ B2,
    const float* __restrict__ Bv,
    bf16* __restrict__ Kp, bf16* __restrict__ Q, bf16* __restrict__ Vp)
{
    __shared__ __align__(16) float sX[256][34];   // pad 34: 2-way read alias (free)

    const int id = blockIdx.x;
    const int mode = id >> 9, sub = id & 511;
    const int b = sub >> 7, nt = sub & 127;
    const int t = threadIdx.x;

    const float* X  = mode == 0 ? rgb : mode == 1 ? dsm : fus;
    const bf16*  W  = mode == 0 ? Wk1 : mode == 1 ? Wk2 : Wv;
    const float* Bs = mode == 0 ? B1  : mode == 1 ? B2  : Bv;

    const float* Xb = X + (size_t)b * 1048576 + (size_t)nt * 32;

    // ---- stage 256c x 32n f32 tile, coalesced float4 ----
#pragma unroll
    for (int i = 0; i < 8; ++i) {
        const int chunk = i * 256 + t;            // 0..2047
        const int c = chunk >> 3, nn4 = (chunk & 7) * 4;
        const f32x4 v4 = *(const f32x4*)(Xb + (size_t)c * 4096 + nn4);
        *(f32x4*)(&sX[c][nn4]) = v4;
    }
    __syncthreads();

    const int lane = t & 63, w = t >> 6;
    const int l15 = lane & 15, g = lane >> 4;
    const int nloc = (w & 1) * 16 + l15;
    const int n = nt * 32 + nloc;
    const int cibase = (w >> 1) * 4;

    const f32x4 z4 = {0.f, 0.f, 0.f, 0.f};
    f32x4 acc[4] = {z4, z4, z4, z4};

#pragma unroll
    for (int ks = 0; ks < 8; ++ks) {
        const int c0 = ks * 32 + g * 8;
        u32x4 xb;
#pragma unroll
        for (int pr = 0; pr < 4; ++pr)
            xb[pr] = cvt_pk_bf16(sX[c0 + 2 * pr][nloc], sX[c0 + 2 * pr + 1][nloc]);
        const bf16x8 bfr = __builtin_bit_cast(bf16x8, xb);
#pragma unroll
        for (int ci = 0; ci < 4; ++ci) {
            bf16x8 af = *(const bf16x8*)(W + ((cibase + ci) * 16 + l15) * 256 + c0);
            acc[ci] = MFMA16(af, bfr, acc[ci]);
        }
    }

#pragma unroll
    for (int ci = 0; ci < 4; ++ci) {
        const int cia = cibase + ci;
        const int j0 = cia * 16 + g * 4;
        const f32x4 bq = *(const f32x4*)(Bs + j0);
        float v0 = acc[ci][0] + bq[0], v1 = acc[ci][1] + bq[1];
        float v2 = acc[ci][2] + bq[2], v3 = acc[ci][3] + bq[3];
        if (mode == 2) {
            const int head = cia >> 2;
            const int bh = b * 2 + head;
            const int dbase = (cia & 3) * 16 + g * 4;
            const int kbg = n >> 6, key = n & 63;
            const int kc = key >> 4, hi2 = (key >> 3) & 1, inner = key & 7;
            bf16* vp = Vp + (size_t)(bh * 64 + kbg) * 4096;
            const float vv[4] = {v0, v1, v2, v3};
#pragma unroll
            for (int rr = 0; rr < 4; ++rr) {
                const int d = dbase + rr;
                const int chunk = (((d >> 5) * 4 + kc) * 2 + hi2) * 32 + (d & 31);
                vp[chunk * 8 + inner] = (bf16)vv[rr];
            }
        } else {
            const int seg = cia >> 1;          // 0:K h0  1:Q h0  2:K h1  3:Q h1
            const int head = seg >> 1;
            const int bh = b * 2 + head;
            const int d0 = (cia & 1) * 16 + g * 4 + (mode == 1 ? 32 : 0);
            u32x2 pk; pk[0] = cvt_pk_bf16(v0, v1); pk[1] = cvt_pk_bf16(v2, v3);
            if (seg & 1) {
                *(u32x2*)(Q + ((size_t)bh * 4096 + n) * 64 + d0) = pk;
            } else {
                const int kbg = n >> 6, r = n & 63;
                const int chunk = (((r >> 5) * 4 + (d0 >> 4)) * 2 + ((d0 >> 3) & 1)) * 32 + (r & 31);
                *(u32x2*)(Kp + (size_t)(bh * 64 + kbg) * 4096 + chunk * 8 + (d0 & 7)) = pk;
            }
        }
    }
}

// ---------------------------------------------------------------------------
// Kernel 2 (attn): split-K x4, LDS-staged K/V, 512-thr/8-wave blocks, m=0
// softmax. [r14-proven verbatim]
// ---------------------------------------------------------------------------
__global__ __launch_bounds__(512) void attn_kernel(
    const bf16* __restrict__ Kp, const bf16* __restrict__ Q,
    const bf16* __restrict__ Vp,
    bf16* __restrict__ Opart, float* __restrict__ Ml)
{
    __shared__ __align__(16) bf16 sK[2][4096];
    __shared__ __align__(16) bf16 sV[2][4096];

    const int id = blockIdx.x;                    // 512
    const int bh = id & 7;                        // XCD-local
    const int qt = (id >> 3) & 15;
    const int s  = id >> 7;                       // 0..3

    const int t = threadIdx.x, lane = t & 63, w = t >> 6;   // w in 0..7
    const int l31 = lane & 31, hi = lane >> 5;
    const int qrow = qt * 256 + w * 32 + l31;
    const int base = bh * 4096;

    bf16x8 qf[4];
    {
        const bf16* qp = Q + ((size_t)(base + qrow)) * 64 + hi * 8;
#pragma unroll
        for (int ds = 0; ds < 4; ++ds) qf[ds] = *(const bf16x8*)(qp + ds * 16);
    }

    f32x16 ot0, ot1;
#pragma unroll
    for (int i = 0; i < 16; ++i) { ot0[i] = 0.f; ot1[i] = 0.f; }
    float lsum = 0.f;

    const bf16* Kblk = Kp + (size_t)(bh * 64 + s * 16) * 4096;
    const bf16* Vblk = Vp + (size_t)(bh * 64 + s * 16) * 4096;
    const int wo = w * 512 + lane * 8;            // covers 4096 elems over 8 waves

#define STAGE(BUF, KBI)                                                      \
    {                                                                        \
        const size_t gb = (size_t)(KBI) * 4096 + wo;                         \
        stage16(Kblk + gb, &sK[BUF][w * 512]);                               \
        stage16(Vblk + gb, &sV[BUF][w * 512]);                               \
    }

    STAGE(0, 0);
    __syncthreads();
    int buf = 0;

    for (int kb = 0; kb < 16; ++kb) {
        if (kb + 1 < 16) {
            if (buf) STAGE(0, kb + 1) else STAGE(1, kb + 1);
        }
        const bf16* Kl = &sK[buf][0];
        const bf16* Vl = &sV[buf][0];

        // ---- per kt: QK^T -> exp2 on accumulator -> sum -> bf16 frags ----
        bf16x8 pa[4];
#pragma unroll
        for (int kt = 0; kt < 2; ++kt) {
            f32x16 a;
#pragma unroll
            for (int i = 0; i < 16; ++i) a[i] = 0.f;
#pragma unroll
            for (int ds = 0; ds < 4; ++ds)
                a = MFMA32(*(const bf16x8*)(Kl + (kt * 4 + ds) * 512 + lane * 8), qf[ds], a);
#pragma unroll
            for (int r = 0; r < 16; ++r) a[r] = vexp2(a[r]);
            lsum += (((a[0] + a[1]) + (a[2] + a[3])) +
                     ((a[4] + a[5]) + (a[6] + a[7]))) +
                    (((a[8] + a[9]) + (a[10] + a[11])) +
                     ((a[12] + a[13]) + (a[14] + a[15])));
            u32 wa0 = cvt_pk_bf16(a[0], a[1]);
            u32 wa1 = cvt_pk_bf16(a[2], a[3]);
            u32 wb0 = cvt_pk_bf16(a[4], a[5]);
            u32 wb1 = cvt_pk_bf16(a[6], a[7]);
            permlane32_swap(wa0, wb0);
            permlane32_swap(wa1, wb1);
            u32x4 pk0; pk0[0] = wa0; pk0[1] = wa1; pk0[2] = wb0; pk0[3] = wb1;
            pa[2 * kt] = __builtin_bit_cast(bf16x8, pk0);
            u32 wc0 = cvt_pk_bf16(a[8], a[9]);
            u32 wc1 = cvt_pk_bf16(a[10], a[11]);
            u32 wd0 = cvt_pk_bf16(a[12], a[13]);
            u32 wd1 = cvt_pk_bf16(a[14], a[15]);
            permlane32_swap(wc0, wd0);
            permlane32_swap(wc1, wd1);
            u32x4 pk1; pk1[0] = wc0; pk1[1] = wc1; pk1[2] = wd0; pk1[3] = wd1;
            pa[2 * kt + 1] = __builtin_bit_cast(bf16x8, pk1);
        }
        // ---- O^T += V^T . P  (frag i=dt*4+ks) ----
#pragma unroll
        for (int ks = 0; ks < 4; ++ks)
            ot0 = MFMA32(*(const bf16x8*)(Vl + ks * 512 + lane * 8), pa[ks], ot0);
#pragma unroll
        for (int ks = 0; ks < 4; ++ks)
            ot1 = MFMA32(*(const bf16x8*)(Vl + (4 + ks) * 512 + lane * 8), pa[ks], ot1);
        __syncthreads();
        buf ^= 1;
    }
#undef STAGE

    // ---- lane-pair lsum merge (no rescale ever happens; pure sum) ----
    const float lt = lsum + __shfl_xor(lsum, 32);

    // ---- store bf16 partials: d = (r&3)+8*(r>>2)+4*hi ----
    const int row = base + qrow;
    bf16* op = Opart + ((size_t)s * 32768 + row) * 64;
#pragma unroll
    for (int a4 = 0; a4 < 4; ++a4) {
        u32x2 p0, p1;
        p0[0] = cvt_pk_bf16(ot0[a4 * 4 + 0], ot0[a4 * 4 + 1]);
        p0[1] = cvt_pk_bf16(ot0[a4 * 4 + 2], ot0[a4 * 4 + 3]);
        *(u32x2*)(op + a4 * 8 + hi * 4) = p0;
        p1[0] = cvt_pk_bf16(ot1[a4 * 4 + 0], ot1[a4 * 4 + 1]);
        p1[1] = cvt_pk_bf16(ot1[a4 * 4 + 2], ot1[a4 * 4 + 3]);
        *(u32x2*)(op + 32 + a4 * 8 + hi * 4) = p1;
    }
    Ml[(size_t)s * 32768 + row] = lt;             // both hi-lanes write same value
}

// ---------------------------------------------------------------------------
// Kernel 3 (out): FUSED combine + projection + BN + sigmoid-gate.
// NEW vs r14: Opart tile (4s x 2h x 16n x 64d = 16KB) LDS-staged with fully
// coalesced 16B loads (rows are 128B-contiguous in memory), rows padded to
// 72 elems (144B -> fragment reads 2-way bank-aliased = free). Replaces the
// 128B-strided global gather (<=25% line utilization, ~4x over-fetch).
// ---------------------------------------------------------------------------
__global__ __launch_bounds__(256) void out_kernel(
    const bf16* __restrict__ Opart, const float* __restrict__ Ml,
    const bf16* __restrict__ Wo, const float* __restrict__ Bo,
    const float* __restrict__ fus, const float* __restrict__ gamma,
    float* __restrict__ out)
{
    __shared__ __align__(16) bf16 sO[4 * 2 * 16 * 72];   // 18 KB

    const int id = blockIdx.x;
    const int b = id >> 8, nt = id & 255;
    const int t = threadIdx.x, lane = t & 63, w = t >> 6;
    const int l15 = lane & 15, g = lane >> 4;
    const int n = nt * 16 + l15;
    const int cibase = w * 4;

    // ---- stage Opart tile: 1152 16B-chunks, coalesced (128B rows) ----
    // chunk = ((s*2+h)*16 + nl)*8 + d16
    for (int chunk = t; chunk < 1152; chunk += 256) {
        const int s = chunk >> 8, rem = chunk & 255;
        const int h = rem >> 7, nl = (rem >> 3) & 15, d16 = chunk & 7;
        const size_t grow = (size_t)s * 32768 + (size_t)(b * 2 + h) * 4096 + nt * 16 + nl;
        const u32x4 v = *(const u32x4*)(Opart + grow * 64 + d16 * 8);
        *(u32x4*)(&sO[(((s * 2 + h) * 16 + nl) * 72) + d16 * 8]) = v;
    }
    __syncthreads();

    // per-(n,h) normalization: rl = 1 / sum_s lsum_s
    float rl[2];
#pragma unroll
    for (int h = 0; h < 2; ++h) {
        const int row = (b * 2 + h) * 4096 + n;
        float L = 0.f;
#pragma unroll
        for (int s = 0; s < 4; ++s) L += Ml[(size_t)s * 32768 + row];
        rl[h] = vrcp(L);
    }

    const f32x4 z4 = {0.f, 0.f, 0.f, 0.f};
    f32x4 acc[4] = {z4, z4, z4, z4};
#pragma unroll
    for (int ks = 0; ks < 4; ++ks) {
        const int h = ks >> 1;
        const int kk = (ks & 1) * 32 + g * 8;     // d-offset within head
        float fc[8] = {0.f, 0.f, 0.f, 0.f, 0.f, 0.f, 0.f, 0.f};
#pragma unroll
        for (int s = 0; s < 4; ++s) {
            const u32x4 pv = *(const u32x4*)(&sO[(((s * 2 + h) * 16 + l15) * 72) + kk]);
#pragma unroll
            for (int pj = 0; pj < 4; ++pj) {
                fc[2 * pj]     += __builtin_bit_cast(float, pv[pj] << 16);
                fc[2 * pj + 1] += __builtin_bit_cast(float, pv[pj] & 0xffff0000u);
            }
        }
        u32x4 pb_;
#pragma unroll
        for (int pj = 0; pj < 4; ++pj)
            pb_[pj] = cvt_pk_bf16(fc[2 * pj] * rl[h], fc[2 * pj + 1] * rl[h]);
        const bf16x8 bfr = __builtin_bit_cast(bf16x8, pb_);
        const int k0 = ks * 32 + g * 8;
#pragma unroll
        for (int ci = 0; ci < 4; ++ci) {
            bf16x8 af = *(const bf16x8*)(Wo + ((cibase + ci) * 16 + l15) * 128 + k0);
            acc[ci] = MFMA16(af, bfr, acc[ci]);
        }
    }
    const float gam = gamma[0];
#pragma unroll
    for (int ci = 0; ci < 4; ++ci) {
        const int c0 = (cibase + ci) * 16 + g * 4;
        const f32x4 bo = *(const f32x4*)(Bo + c0);
#pragma unroll
        for (int r = 0; r < 4; ++r) {
            const int c = c0 + r;
            const size_t off = ((size_t)(b * 256 + c)) * 4096 + n;
            const float v = acc[ci][r] + bo[r];
            const float sg = vrcp(1.0f + vexp2(-v * LOG2E));
            out[off] = fus[off] * fmaf(sg, gam, 1.0f);
        }
    }
}

// ---------------------------------------------------------------------------
extern "C" void kernel_launch(void* const* d_in, const int* in_sizes, int n_in,
                              void* d_out, int out_size, void* d_ws, size_t ws_size,
                              hipStream_t stream)
{
    (void)in_sizes; (void)n_in; (void)out_size; (void)ws_size;
    const float* fusion = (const float*)d_in[0];
    const float* rgb    = (const float*)d_in[1];
    const float* dsm    = (const float*)d_in[2];
    const float* bn1w = (const float*)d_in[3];
    const float* bn1b = (const float*)d_in[4];
    const float* bn1m = (const float*)d_in[5];
    const float* bn1v = (const float*)d_in[6];
    const float* bn2w = (const float*)d_in[7];
    const float* bn2b = (const float*)d_in[8];
    const float* bn2m = (const float*)d_in[9];
    const float* bn2v = (const float*)d_in[10];
    const float* kq1w = (const float*)d_in[11];
    const float* kq1b = (const float*)d_in[12];
    const float* kq2w = (const float*)d_in[13];
    const float* kq2b = (const float*)d_in[14];
    const float* vw   = (const float*)d_in[15];
    const float* vb   = (const float*)d_in[16];
    const float* outw = (const float*)d_in[17];
    const float* outb = (const float*)d_in[18];
    const float* bnlw = (const float*)d_in[19];
    const float* bnlb = (const float*)d_in[20];
    const float* bnlm = (const float*)d_in[21];
    const float* bnlv = (const float*)d_in[22];
    const float* gamma = (const float*)d_in[23];

    char* ws = (char*)d_ws;
    size_t off = 0;
    auto alloc = [&](size_t bytes) { char* p = ws + off; off = (off + bytes + 255) & ~(size_t)255; return p; };
    bf16* Wk1 = (bf16*)alloc(128 * 256 * 2);
    bf16* Wk2 = (bf16*)alloc(128 * 256 * 2);
    bf16* Wv  = (bf16*)alloc(128 * 256 * 2);
    bf16* Wo  = (bf16*)alloc(256 * 128 * 2);
    float* B1 = (float*)alloc(128 * 4);
    float* B2 = (float*)alloc(128 * 4);
    float* Bv = (float*)alloc(128 * 4);
    float* Bo = (float*)alloc(256 * 4);
    bf16* Kp    = (bf16*)alloc((size_t)8 * 64 * 4096 * 2);          // 4 MB
    bf16* Q     = (bf16*)alloc((size_t)8 * 4096 * 64 * 2);          // 4 MB
    bf16* Vp    = (bf16*)alloc((size_t)8 * 64 * 4096 * 2);          // 4 MB
    bf16* Opart = (bf16*)alloc((size_t)4 * 8 * 4096 * 64 * 2);      // 16 MB
    float* Ml   = (float*)alloc((size_t)4 * 8 * 4096 * 4);          // 0.5 MB

    wprep_kernel<<<640, 64, 0, stream>>>(
        kq1w, kq1b, bn1w, bn1b, bn1m, bn1v,
        kq2w, kq2b, bn2w, bn2b, bn2m, bn2v,
        vw, vb, outw, outb, bnlw, bnlb, bnlm, bnlv,
        Wk1, Wk2, Wv, Wo, B1, B2, Bv, Bo);
    prep_kernel<<<1536, 256, 0, stream>>>(rgb, dsm, fusion,
        Wk1, Wk2, Wv, B1, B2, Bv, Kp, Q, Vp);
    attn_kernel<<<512, 512, 0, stream>>>(Kp, Q, Vp, Opart, Ml);
    out_kernel<<<1024, 256, 0, stream>>>(Opart, Ml, Wo, Bo, fusion, gamma, (float*)d_out);
}